// Round 3
// baseline (320.493 us; speedup 1.0000x reference)
//
#include <hip/hip_runtime.h>
#include <math.h>
#include <stdint.h>

#define NB 16
#define NS 2048
#define NT 1024
#define NE 256
#define ND 256
#define NM (NB * NT)  // 16384
#define KF (NE + ND)  // 512

typedef short sh8 __attribute__((ext_vector_type(8)));
typedef float f4v __attribute__((ext_vector_type(4)));

// ---------------- dtype helpers ----------------
static __device__ __forceinline__ float bf2f(unsigned short u) {
    union { unsigned int i; float f; } v;
    v.i = ((unsigned int)u) << 16;
    return v.f;
}
static __device__ __forceinline__ unsigned short f2bf(float f) {
    union { unsigned int i; float f; } v;
    v.f = f;
    unsigned int x = v.i;
    x += 0x7FFFu + ((x >> 16) & 1u);  // round-to-nearest-even
    return (unsigned short)(x >> 16);
}
static __device__ __forceinline__ float4 load4(const void* p, int isbf, long idx) {
    if (isbf) {
        const unsigned short* h = (const unsigned short*)p + idx;
        ushort4 u = *(const ushort4*)h;
        return make_float4(bf2f(u.x), bf2f(u.y), bf2f(u.z), bf2f(u.w));
    }
    const float* f = (const float*)p + idx;
    return *(const float4*)f;
}
static __device__ __forceinline__ int mvalid(const void* m, int kind, int b, int s) {
    long idx = (long)b * NS + s;
    switch (kind) {
        case 0:  return ((const unsigned char*)m)[idx] != 0;
        case 1:  return ((const int*)m)[idx] != 0;
        case 2:  return ((const unsigned short*)m)[idx] != 0;
        default: return ((const unsigned int*)m)[idx] != 0;
    }
}

// ---------------- dtype detector ----------------
__global__ void k_detect(const void* __restrict__ enc_raw,
                         const void* __restrict__ mask_raw,
                         int* __restrict__ flags) {
    __shared__ int cnt;
    if (threadIdx.x == 0) cnt = 0;
    __syncthreads();
    const unsigned short* h = (const unsigned short*)enc_raw;
    int local = 0;
    for (int i = threadIdx.x; i < 4096; i += 256) {
        int ex = (h[i] >> 7) & 0xFF;
        if (ex >= 97 && ex <= 157) local++;
    }
    atomicAdd(&cnt, local);
    __syncthreads();
    if (threadIdx.x == 0) {
        int isbf = (cnt >= 3700) ? 1 : 0;
        const unsigned char* mb = (const unsigned char*)mask_raw;
        int kind;
        if (mb[1] == 0x3F)                       kind = 2;
        else if (mb[3] == 0x3F && mb[1] == 0)    kind = 3;
        else if (mb[1] == 1)                     kind = 0;
        else if (mb[4] == 1 || mb[8] == 1)       kind = 1;
        else                                     kind = (mb[NS] == 1) ? 0 : 1;
        flags[0] = isbf;
        flags[1] = kind;
    }
}

// ---------------- generic hi/lo bf16 split (8 elems / thread) ----------------
__global__ __launch_bounds__(256) void k_split(const void* __restrict__ src,
                                               const int* __restrict__ flags,
                                               unsigned short* __restrict__ hh,
                                               unsigned short* __restrict__ ll) {
    const int isbf = flags[0];
    const long i = ((long)blockIdx.x * 256 + threadIdx.x) * 8;
    if (isbf) {
        sh8 v = *(const sh8*)((const unsigned short*)src + i);
        *(sh8*)(hh + i) = v;   // ll never read in bf16 path
    } else {
        const float* f = (const float*)src + i;
        sh8 hv, lv;
#pragma unroll
        for (int j = 0; j < 8; ++j) {
            float x = f[j];
            unsigned short h = f2bf(x);
            hv[j] = (short)h;
            lv[j] = (short)f2bf(x - bf2f(h));
        }
        *(sh8*)(hh + i) = hv;
        *(sh8*)(ll + i) = lv;
    }
}

// ---------------- transpose + split W_fin: (512,256) -> [n][f] hi/lo ----------------
__global__ __launch_bounds__(256) void k_twf(const void* __restrict__ Wfin,
                                             const int* __restrict__ flags,
                                             unsigned short* __restrict__ wfh,
                                             unsigned short* __restrict__ wfl) {
    const int isbf = flags[0];
    __shared__ float T[64][68];
    const int f0 = blockIdx.x * 64, n0 = blockIdx.y * 64;
    const int tid = threadIdx.x;
#pragma unroll
    for (int i = 0; i < 4; ++i) {
        int idx = tid + i * 256;
        int r = idx >> 4, c4 = (idx & 15) << 2;
        float4 v = load4(Wfin, isbf, (long)(f0 + r) * ND + n0 + c4);
        T[r][c4] = v.x; T[r][c4 + 1] = v.y; T[r][c4 + 2] = v.z; T[r][c4 + 3] = v.w;
    }
    __syncthreads();
#pragma unroll
    for (int i = 0; i < 4; ++i) {
        int idx = tid + i * 256;
        int n = idx >> 4, f4 = (idx & 15) << 2;
        ushort4 hv, lv;
        float x;
        x = T[f4 + 0][n]; hv.x = f2bf(x); lv.x = f2bf(x - bf2f(hv.x));
        x = T[f4 + 1][n]; hv.y = f2bf(x); lv.y = f2bf(x - bf2f(hv.y));
        x = T[f4 + 2][n]; hv.z = f2bf(x); lv.z = f2bf(x - bf2f(hv.z));
        x = T[f4 + 3][n]; hv.w = f2bf(x); lv.w = f2bf(x - bf2f(hv.w));
        long base = (long)(n0 + n) * KF + f0 + f4;
        *(ushort4*)&wfh[base] = hv;
        *(ushort4*)&wfl[base] = lv;
    }
}

// ---------------- K1: qproj = dec @ Wenc^T via MFMA bf16x3 ----------------
// grid (NM/64, NE/64), 4 waves; wave quadrant 32x32 (2x2 16x16 frags).
__global__ __launch_bounds__(256) void k_q_m(const unsigned short* __restrict__ dh,
                                             const unsigned short* __restrict__ dl,
                                             const unsigned short* __restrict__ wh,
                                             const unsigned short* __restrict__ wl,
                                             const int* __restrict__ flags,
                                             unsigned short* __restrict__ qh,
                                             unsigned short* __restrict__ ql) {
    const int isbf = flags[0];
    const int lane = threadIdx.x & 63, wid = threadIdx.x >> 6;
    const int lr = lane & 15, lg = lane >> 4;
    const long m0 = (long)blockIdx.x * 64 + (wid & 1) * 32;
    const int  n0 = blockIdx.y * 64 + (wid >> 1) * 32;
    const unsigned short* Ah = dh + (m0 + lr) * ND + lg * 8;
    const unsigned short* Al = dl + (m0 + lr) * ND + lg * 8;
    const unsigned short* Bh = wh + (long)(n0 + lr) * ND + lg * 8;
    const unsigned short* Bl = wl + (long)(n0 + lr) * ND + lg * 8;
    f4v acc[2][2];
#pragma unroll
    for (int i = 0; i < 2; ++i)
#pragma unroll
        for (int j = 0; j < 2; ++j) acc[i][j] = (f4v){0.f, 0.f, 0.f, 0.f};
    if (isbf) {
#pragma unroll
        for (int k8 = 0; k8 < 8; ++k8) {
            const int ko = k8 * 32;
            sh8 a0 = *(const sh8*)(Ah + ko);
            sh8 a1 = *(const sh8*)(Ah + 16 * ND + ko);
            sh8 b0 = *(const sh8*)(Bh + ko);
            sh8 b1 = *(const sh8*)(Bh + 16 * ND + ko);
            acc[0][0] = __builtin_amdgcn_mfma_f32_16x16x32_bf16(a0, b0, acc[0][0], 0, 0, 0);
            acc[0][1] = __builtin_amdgcn_mfma_f32_16x16x32_bf16(a0, b1, acc[0][1], 0, 0, 0);
            acc[1][0] = __builtin_amdgcn_mfma_f32_16x16x32_bf16(a1, b0, acc[1][0], 0, 0, 0);
            acc[1][1] = __builtin_amdgcn_mfma_f32_16x16x32_bf16(a1, b1, acc[1][1], 0, 0, 0);
        }
    } else {
#pragma unroll
        for (int k8 = 0; k8 < 8; ++k8) {
            const int ko = k8 * 32;
            sh8 a0 = *(const sh8*)(Ah + ko);
            sh8 a1 = *(const sh8*)(Ah + 16 * ND + ko);
            sh8 b0 = *(const sh8*)(Bh + ko);
            sh8 b1 = *(const sh8*)(Bh + 16 * ND + ko);
            sh8 la0 = *(const sh8*)(Al + ko);
            sh8 la1 = *(const sh8*)(Al + 16 * ND + ko);
            sh8 lb0 = *(const sh8*)(Bl + ko);
            sh8 lb1 = *(const sh8*)(Bl + 16 * ND + ko);
            acc[0][0] = __builtin_amdgcn_mfma_f32_16x16x32_bf16(a0, b0, acc[0][0], 0, 0, 0);
            acc[0][0] = __builtin_amdgcn_mfma_f32_16x16x32_bf16(la0, b0, acc[0][0], 0, 0, 0);
            acc[0][0] = __builtin_amdgcn_mfma_f32_16x16x32_bf16(a0, lb0, acc[0][0], 0, 0, 0);
            acc[0][1] = __builtin_amdgcn_mfma_f32_16x16x32_bf16(a0, b1, acc[0][1], 0, 0, 0);
            acc[0][1] = __builtin_amdgcn_mfma_f32_16x16x32_bf16(la0, b1, acc[0][1], 0, 0, 0);
            acc[0][1] = __builtin_amdgcn_mfma_f32_16x16x32_bf16(a0, lb1, acc[0][1], 0, 0, 0);
            acc[1][0] = __builtin_amdgcn_mfma_f32_16x16x32_bf16(a1, b0, acc[1][0], 0, 0, 0);
            acc[1][0] = __builtin_amdgcn_mfma_f32_16x16x32_bf16(la1, b0, acc[1][0], 0, 0, 0);
            acc[1][0] = __builtin_amdgcn_mfma_f32_16x16x32_bf16(a1, lb0, acc[1][0], 0, 0, 0);
            acc[1][1] = __builtin_amdgcn_mfma_f32_16x16x32_bf16(a1, b1, acc[1][1], 0, 0, 0);
            acc[1][1] = __builtin_amdgcn_mfma_f32_16x16x32_bf16(la1, b1, acc[1][1], 0, 0, 0);
            acc[1][1] = __builtin_amdgcn_mfma_f32_16x16x32_bf16(a1, lb1, acc[1][1], 0, 0, 0);
        }
    }
#pragma unroll
    for (int mi = 0; mi < 2; ++mi)
#pragma unroll
        for (int r = 0; r < 4; ++r) {
            long rowb = (m0 + mi * 16 + lg * 4 + r) * NE + n0 + lr;
#pragma unroll
            for (int ni = 0; ni < 2; ++ni) {
                float v = acc[mi][ni][r];
                unsigned short h = f2bf(v);
                qh[rowb + ni * 16] = h;
                ql[rowb + ni * 16] = f2bf(v - bf2f(h));
            }
        }
}

// ---------------- K2: MFMA flash attention (unchanged core; bf16 hi/lo ctx out) ----
__global__ __launch_bounds__(256, 2) void k_attn(
    const unsigned short* qh, const unsigned short* ql,
    const unsigned short* __restrict__ eh, const unsigned short* __restrict__ el,
    const void* __restrict__ mask, const int* __restrict__ flags,
    unsigned short* ch, unsigned short* cl,
    float* __restrict__ pctx, float* __restrict__ Mp, float* __restrict__ Lp)
{
    const int isbf  = flags[0];
    const int mkind = flags[1];
    const int b  = blockIdx.y;
    const int t0 = blockIdx.x * 32;
    const int part = blockIdx.z, nparts = gridDim.z;
    const int tid  = threadIdx.x;
    const int lane = tid & 63;
    const int wid  = tid >> 6;
    const int th = wid & 1;      // t-half
    const int sh = wid >> 1;     // s-half (scores) / e-half (PV)
    const int lr = lane & 15;
    const int lg = lane >> 4;

    __shared__ __align__(16) unsigned short EHR[32][264];
    __shared__ __align__(16) unsigned short ELR[32][264];
    __shared__ __align__(16) unsigned short VT[2][256][40];
    __shared__ __align__(16) float PBs[32][36];
    __shared__ float hm[2][32];
    __shared__ float hs[2][32];
    __shared__ int s_len;

    if (tid == 0) s_len = 0;
    __syncthreads();
    {
        int c = 0;
#pragma unroll
        for (int j = 0; j < 8; ++j) c += mvalid(mask, mkind, b, tid * 8 + j);
        atomicAdd(&s_len, c);
    }
    __syncthreads();
    const int len  = s_len;
    const int s_lo = part * (NS / nparts);
    const int s_hi = min(s_lo + NS / nparts, len);
    const int ntiles = (s_hi > s_lo) ? ((s_hi - s_lo + 31) >> 5) : 0;
    const long mrow = (long)part * NM + (long)b * NT + t0;
    if (ntiles == 0) {
        if (nparts > 1 && tid < 32) { Mp[mrow + tid] = -INFINITY; Lp[mrow + tid] = 0.f; }
        return;
    }

    sh8 qhf[8], qlf[8];
    {
        const unsigned short* qp  = qh + ((long)b * NT + t0 + th * 16 + lr) * NE + lg * 8;
        const unsigned short* qp2 = ql + ((long)b * NT + t0 + th * 16 + lr) * NE + lg * 8;
#pragma unroll
        for (int k8 = 0; k8 < 8; ++k8) {
            qhf[k8] = *(const sh8*)(qp  + k8 * 32);
            qlf[k8] = *(const sh8*)(qp2 + k8 * 32);
        }
    }

    f4v O[8];
#pragma unroll
    for (int et = 0; et < 8; ++et) O[et] = (f4v){0.f, 0.f, 0.f, 0.f};
    float Mreg4[4], L4[4], MregP = -INFINITY;
#pragma unroll
    for (int r = 0; r < 4; ++r) { Mreg4[r] = -INFINITY; L4[r] = 0.f; }

    const int ss = tid >> 3;
    const int ee = (tid & 7) * 8;
    const int swzw = ((tid & 7) & 3) << 3;

    sh8 rh[4], rl[4];
    {
        const unsigned short* eg = eh + ((long)b * NS + s_lo + ss) * NE;
#pragma unroll
        for (int c = 0; c < 4; ++c) rh[c] = *(const sh8*)(eg + ee + c * 64);
        if (!isbf) {
            const unsigned short* eg2 = el + ((long)b * NS + s_lo + ss) * NE;
#pragma unroll
            for (int c = 0; c < 4; ++c) rl[c] = *(const sh8*)(eg2 + ee + c * 64);
        }
#pragma unroll
        for (int c = 0; c < 4; ++c) {
            const int e0 = ee + c * 64;
            *(sh8*)&EHR[ss][e0] = rh[c];
            if (!isbf) *(sh8*)&ELR[ss][e0] = rl[c];
            const int cs = ss ^ swzw;
#pragma unroll
            for (int j = 0; j < 8; ++j) VT[0][e0 + j][cs] = (unsigned short)rh[c][j];
        }
    }
    int cur = 0;

    for (int it = 0; it < ntiles; ++it) {
        const int s0 = s_lo + it * 32;
        __syncthreads();   // B2: stage(it) visible
        f4v cacc = (f4v){0.f, 0.f, 0.f, 0.f};
        {
            const unsigned short* ep = &EHR[sh * 16 + lr][lg * 8];
            const unsigned short* lp = &ELR[sh * 16 + lr][lg * 8];
            if (isbf) {
#pragma unroll
                for (int k8 = 0; k8 < 8; ++k8) {
                    sh8 ea = *(const sh8*)(ep + k8 * 32);
                    cacc = __builtin_amdgcn_mfma_f32_16x16x32_bf16(ea, qhf[k8], cacc, 0, 0, 0);
                    cacc = __builtin_amdgcn_mfma_f32_16x16x32_bf16(ea, qlf[k8], cacc, 0, 0, 0);
                }
            } else {
#pragma unroll
                for (int k8 = 0; k8 < 8; ++k8) {
                    sh8 ea = *(const sh8*)(ep + k8 * 32);
                    sh8 eb = *(const sh8*)(lp + k8 * 32);
                    cacc = __builtin_amdgcn_mfma_f32_16x16x32_bf16(ea, qhf[k8], cacc, 0, 0, 0);
                    cacc = __builtin_amdgcn_mfma_f32_16x16x32_bf16(ea, qlf[k8], cacc, 0, 0, 0);
                    cacc = __builtin_amdgcn_mfma_f32_16x16x32_bf16(eb, qhf[k8], cacc, 0, 0, 0);
                }
            }
        }
        float sc[4];
#pragma unroll
        for (int r = 0; r < 4; ++r) {
            int sl = sh * 16 + lg * 4 + r;
            sc[r] = (s0 + sl < len) ? cacc[r] : -INFINITY;
        }
        float m4 = fmaxf(fmaxf(sc[0], sc[1]), fmaxf(sc[2], sc[3]));
        m4 = fmaxf(m4, __shfl_xor(m4, 16));
        m4 = fmaxf(m4, __shfl_xor(m4, 32));
        float p[4], ps = 0.f;
#pragma unroll
        for (int r = 0; r < 4; ++r) {
            p[r] = (sc[r] == -INFINITY) ? 0.f : __expf(sc[r] - m4);
            ps += p[r];
        }
        ps += __shfl_xor(ps, 16);
        ps += __shfl_xor(ps, 32);
        if (lane < 16) { hm[sh][th * 16 + lane] = m4; hs[sh][th * 16 + lane] = ps; }
        *(float4*)&PBs[th * 16 + lr][sh * 16 + lg * 4] = make_float4(p[0], p[1], p[2], p[3]);
        __syncthreads();   // B5: publish visible
        float f0, f1, al[4];
        {
            const int tP = th * 16 + lr;
            float h0 = hm[0][tP], h1 = hm[1][tP];
            float Mn = fmaxf(MregP, fmaxf(h0, h1));
            f0 = __expf(h0 - Mn);
            f1 = __expf(h1 - Mn);
            MregP = Mn;
        }
#pragma unroll
        for (int r = 0; r < 4; ++r) {
            const int t4 = th * 16 + lg * 4 + r;
            float g0 = hm[0][t4], g1 = hm[1][t4];
            float Mn = fmaxf(Mreg4[r], fmaxf(g0, g1));
            al[r] = __expf(Mreg4[r] - Mn);
            L4[r] = L4[r] * al[r] + hs[0][t4] * __expf(g0 - Mn) + hs[1][t4] * __expf(g1 - Mn);
            Mreg4[r] = Mn;
        }
        const int more = (it + 1 < ntiles);
        if (more) {
            const unsigned short* eg = eh + ((long)b * NS + s0 + 32 + ss) * NE;
#pragma unroll
            for (int c = 0; c < 4; ++c) rh[c] = *(const sh8*)(eg + ee + c * 64);
            if (!isbf) {
                const unsigned short* eg2 = el + ((long)b * NS + s0 + 32 + ss) * NE;
#pragma unroll
                for (int c = 0; c < 4; ++c) rl[c] = *(const sh8*)(eg2 + ee + c * 64);
            }
        }
        {
            const float fsc = (lg < 2) ? f0 : f1;
            f4v pA = *(const f4v*)&PBs[th * 16 + lr][lg * 8];
            f4v pB = *(const f4v*)&PBs[th * 16 + lr][lg * 8 + 4];
            sh8 pf;
#pragma unroll
            for (int j = 0; j < 4; ++j) {
                pf[j]     = (short)f2bf(pA[j] * fsc);
                pf[4 + j] = (short)f2bf(pB[j] * fsc);
            }
            f4v alv = (f4v){al[0], al[1], al[2], al[3]};
#pragma unroll
            for (int et = 0; et < 8; ++et) O[et] *= alv;
#pragma unroll
            for (int et = 0; et < 8; ++et) {
                const int row = sh * 128 + et * 16 + lr;
                sh8 vf = *(const sh8*)&VT[cur][row][(lg ^ ((row >> 3) & 3)) * 8];
                O[et] = __builtin_amdgcn_mfma_f32_16x16x32_bf16(pf, vf, O[et], 0, 0, 0);
            }
        }
        if (more) {
#pragma unroll
            for (int c = 0; c < 4; ++c) {
                const int e0 = ee + c * 64;
                *(sh8*)&EHR[ss][e0] = rh[c];
                if (!isbf) *(sh8*)&ELR[ss][e0] = rl[c];
                const int cs = ss ^ swzw;
#pragma unroll
                for (int j = 0; j < 8; ++j) VT[cur ^ 1][e0 + j][cs] = (unsigned short)rh[c][j];
            }
            cur ^= 1;
        }
    }
    // ---- epilogue ----
    if (nparts == 1) {
        f4v inv;
#pragma unroll
        for (int r = 0; r < 4; ++r) inv[r] = 1.0f / L4[r];
#pragma unroll
        for (int et = 0; et < 8; ++et) {
            f4v ov = O[et] * inv;
            long rbase = ((long)b * NT + t0 + th * 16 + lg * 4) * NE + sh * 128 + et * 16 + lr;
#pragma unroll
            for (int r = 0; r < 4; ++r) {
                float v = ov[r];
                unsigned short h = f2bf(v);
                ch[rbase + (long)r * NE] = h;
                cl[rbase + (long)r * NE] = f2bf(v - bf2f(h));
            }
        }
    } else {
        float* op = pctx + (long)part * NM * NE;
#pragma unroll
        for (int et = 0; et < 8; ++et) {
            long rbase = ((long)b * NT + t0 + th * 16 + lg * 4) * NE + sh * 128 + et * 16 + lr;
#pragma unroll
            for (int r = 0; r < 4; ++r)
                op[rbase + (long)r * NE] = O[et][r];
        }
        if (sh == 0 && lr == 0) {
#pragma unroll
            for (int r = 0; r < 4; ++r) {
                Mp[mrow + th * 16 + lg * 4 + r] = Mreg4[r];
                Lp[mrow + th * 16 + lg * 4 + r] = L4[r];
            }
        }
    }
}

// ---------------- combine split-s partials -> ctx bf16 hi/lo ----------------
__global__ __launch_bounds__(256) void k_comb(const float* __restrict__ pctx,
                                              const float* __restrict__ Mp,
                                              const float* __restrict__ Lp,
                                              int nparts,
                                              unsigned short* __restrict__ ch,
                                              unsigned short* __restrict__ cl) {
    const long m = (long)blockIdx.x * 8 + (threadIdx.x >> 5);
    const int  e0 = (threadIdx.x & 31) * 8;
    float Mv[4], Lv[4];
    float M = -INFINITY;
    for (int p = 0; p < nparts; ++p) {
        Mv[p] = Mp[(long)p * NM + m];
        Lv[p] = Lp[(long)p * NM + m];
        if (Lv[p] > 0.f) M = fmaxf(M, Mv[p]);
    }
    float L = 0.f, w[4];
    for (int p = 0; p < nparts; ++p) {
        w[p] = (Lv[p] > 0.f) ? __expf(Mv[p] - M) : 0.f;
        L += Lv[p] * w[p];
    }
    float o[8] = {};
    for (int p = 0; p < nparts; ++p) {
        if (w[p] > 0.f) {
            const float* src = pctx + (long)p * NM * NE + m * NE + e0;
            f4v a = *(const f4v*)src;
            f4v c = *(const f4v*)(src + 4);
#pragma unroll
            for (int j = 0; j < 4; ++j) { o[j] += a[j] * w[p]; o[4 + j] += c[j] * w[p]; }
        }
    }
    const float inv = 1.0f / L;
    unsigned short hv[8], lv[8];
#pragma unroll
    for (int j = 0; j < 8; ++j) {
        float v = o[j] * inv;
        unsigned short h = f2bf(v);
        hv[j] = h;
        lv[j] = f2bf(v - bf2f(h));
    }
    long base = m * NE + e0;
    *(ushort4*)&ch[base]     = *(ushort4*)&hv[0];
    *(ushort4*)&ch[base + 4] = *(ushort4*)&hv[4];
    *(ushort4*)&cl[base]     = *(ushort4*)&lv[0];
    *(ushort4*)&cl[base + 4] = *(ushort4*)&lv[4];
}

// ---------------- K3: out = tanh([ctx | dec] @ W_fin) via MFMA bf16x3 ----------------
__global__ __launch_bounds__(256) void k_fin_m(const unsigned short* __restrict__ ch,
                                               const unsigned short* __restrict__ cl,
                                               const unsigned short* __restrict__ dh,
                                               const unsigned short* __restrict__ dl,
                                               const unsigned short* __restrict__ wh,
                                               const unsigned short* __restrict__ wl,
                                               const int* __restrict__ flags,
                                               void* __restrict__ out) {
    const int isbf = flags[0];
    const int lane = threadIdx.x & 63, wid = threadIdx.x >> 6;
    const int lr = lane & 15, lg = lane >> 4;
    const long m0 = (long)blockIdx.x * 64 + (wid & 1) * 32;
    const int  n0 = blockIdx.y * 64 + (wid >> 1) * 32;
    const unsigned short* Bh = wh + (long)(n0 + lr) * KF + lg * 8;
    const unsigned short* Bl = wl + (long)(n0 + lr) * KF + lg * 8;
    f4v acc[2][2];
#pragma unroll
    for (int i = 0; i < 2; ++i)
#pragma unroll
        for (int j = 0; j < 2; ++j) acc[i][j] = (f4v){0.f, 0.f, 0.f, 0.f};

    // phase 1: ctx half (A lo always valid; B lo only if fp32 weights)
    {
        const unsigned short* Ah = ch + (m0 + lr) * NE + lg * 8;
        const unsigned short* Al = cl + (m0 + lr) * NE + lg * 8;
#pragma unroll
        for (int k8 = 0; k8 < 8; ++k8) {
            const int ko = k8 * 32;
            sh8 a0 = *(const sh8*)(Ah + ko);
            sh8 a1 = *(const sh8*)(Ah + 16 * NE + ko);
            sh8 la0 = *(const sh8*)(Al + ko);
            sh8 la1 = *(const sh8*)(Al + 16 * NE + ko);
            sh8 b0 = *(const sh8*)(Bh + ko);
            sh8 b1 = *(const sh8*)(Bh + 16 * KF + ko);
            acc[0][0] = __builtin_amdgcn_mfma_f32_16x16x32_bf16(a0, b0, acc[0][0], 0, 0, 0);
            acc[0][0] = __builtin_amdgcn_mfma_f32_16x16x32_bf16(la0, b0, acc[0][0], 0, 0, 0);
            acc[0][1] = __builtin_amdgcn_mfma_f32_16x16x32_bf16(a0, b1, acc[0][1], 0, 0, 0);
            acc[0][1] = __builtin_amdgcn_mfma_f32_16x16x32_bf16(la0, b1, acc[0][1], 0, 0, 0);
            acc[1][0] = __builtin_amdgcn_mfma_f32_16x16x32_bf16(a1, b0, acc[1][0], 0, 0, 0);
            acc[1][0] = __builtin_amdgcn_mfma_f32_16x16x32_bf16(la1, b0, acc[1][0], 0, 0, 0);
            acc[1][1] = __builtin_amdgcn_mfma_f32_16x16x32_bf16(a1, b1, acc[1][1], 0, 0, 0);
            acc[1][1] = __builtin_amdgcn_mfma_f32_16x16x32_bf16(la1, b1, acc[1][1], 0, 0, 0);
            if (!isbf) {
                sh8 lb0 = *(const sh8*)(Bl + ko);
                sh8 lb1 = *(const sh8*)(Bl + 16 * KF + ko);
                acc[0][0] = __builtin_amdgcn_mfma_f32_16x16x32_bf16(a0, lb0, acc[0][0], 0, 0, 0);
                acc[0][1] = __builtin_amdgcn_mfma_f32_16x16x32_bf16(a0, lb1, acc[0][1], 0, 0, 0);
                acc[1][0] = __builtin_amdgcn_mfma_f32_16x16x32_bf16(a1, lb0, acc[1][0], 0, 0, 0);
                acc[1][1] = __builtin_amdgcn_mfma_f32_16x16x32_bf16(a1, lb1, acc[1][1], 0, 0, 0);
            }
        }
    }
    // phase 2: dec half (A lo / B lo only if fp32 inputs)
    {
        const unsigned short* Ah = dh + (m0 + lr) * ND + lg * 8;
        const unsigned short* Al = dl + (m0 + lr) * ND + lg * 8;
        const unsigned short* B2h = Bh + NE;
        const unsigned short* B2l = Bl + NE;
#pragma unroll
        for (int k8 = 0; k8 < 8; ++k8) {
            const int ko = k8 * 32;
            sh8 a0 = *(const sh8*)(Ah + ko);
            sh8 a1 = *(const sh8*)(Ah + 16 * ND + ko);
            sh8 b0 = *(const sh8*)(B2h + ko);
            sh8 b1 = *(const sh8*)(B2h + 16 * KF + ko);
            acc[0][0] = __builtin_amdgcn_mfma_f32_16x16x32_bf16(a0, b0, acc[0][0], 0, 0, 0);
            acc[0][1] = __builtin_amdgcn_mfma_f32_16x16x32_bf16(a0, b1, acc[0][1], 0, 0, 0);
            acc[1][0] = __builtin_amdgcn_mfma_f32_16x16x32_bf16(a1, b0, acc[1][0], 0, 0, 0);
            acc[1][1] = __builtin_amdgcn_mfma_f32_16x16x32_bf16(a1, b1, acc[1][1], 0, 0, 0);
            if (!isbf) {
                sh8 la0 = *(const sh8*)(Al + ko);
                sh8 la1 = *(const sh8*)(Al + 16 * ND + ko);
                sh8 lb0 = *(const sh8*)(B2l + ko);
                sh8 lb1 = *(const sh8*)(B2l + 16 * KF + ko);
                acc[0][0] = __builtin_amdgcn_mfma_f32_16x16x32_bf16(la0, b0, acc[0][0], 0, 0, 0);
                acc[0][0] = __builtin_amdgcn_mfma_f32_16x16x32_bf16(a0, lb0, acc[0][0], 0, 0, 0);
                acc[0][1] = __builtin_amdgcn_mfma_f32_16x16x32_bf16(la0, b1, acc[0][1], 0, 0, 0);
                acc[0][1] = __builtin_amdgcn_mfma_f32_16x16x32_bf16(a0, lb1, acc[0][1], 0, 0, 0);
                acc[1][0] = __builtin_amdgcn_mfma_f32_16x16x32_bf16(la1, b0, acc[1][0], 0, 0, 0);
                acc[1][0] = __builtin_amdgcn_mfma_f32_16x16x32_bf16(a1, lb0, acc[1][0], 0, 0, 0);
                acc[1][1] = __builtin_amdgcn_mfma_f32_16x16x32_bf16(la1, b1, acc[1][1], 0, 0, 0);
                acc[1][1] = __builtin_amdgcn_mfma_f32_16x16x32_bf16(a1, lb1, acc[1][1], 0, 0, 0);
            }
        }
    }
    if (isbf) {
        unsigned short* o = (unsigned short*)out;
#pragma unroll
        for (int mi = 0; mi < 2; ++mi)
#pragma unroll
            for (int r = 0; r < 4; ++r) {
                long rowb = (m0 + mi * 16 + lg * 4 + r) * ND + n0 + lr;
#pragma unroll
                for (int ni = 0; ni < 2; ++ni)
                    o[rowb + ni * 16] = f2bf(tanhf(acc[mi][ni][r]));
            }
    } else {
        float* o = (float*)out;
#pragma unroll
        for (int mi = 0; mi < 2; ++mi)
#pragma unroll
            for (int r = 0; r < 4; ++r) {
                long rowb = (m0 + mi * 16 + lg * 4 + r) * ND + n0 + lr;
#pragma unroll
                for (int ni = 0; ni < 2; ++ni)
                    o[rowb + ni * 16] = tanhf(acc[mi][ni][r]);
            }
    }
}

extern "C" void kernel_launch(void* const* d_in, const int* in_sizes, int n_in,
                              void* d_out, int out_size, void* d_ws, size_t ws_size,
                              hipStream_t stream) {
    const void* enc  = d_in[0];  // (B,S,E)
    const void* dec  = d_in[1];  // (B,T,D)
    const void* mask = d_in[2];  // (B,S) bool
    const void* Wenc = d_in[3];  // (E,D)
    const void* Wfin = d_in[4];  // (E+D,D)

    unsigned short* ehb = (unsigned short*)d_ws;
    unsigned short* elb = ehb + (size_t)NB * NS * NE;
    unsigned short* qhb = elb + (size_t)NB * NS * NE;   // reused as ctx-hi after k_attn
    unsigned short* qlb = qhb + (size_t)NM * NE;        // reused as ctx-lo
    unsigned short* dhb = qlb + (size_t)NM * NE;
    unsigned short* dlb = dhb + (size_t)NM * ND;
    unsigned short* weh = dlb + (size_t)NM * ND;
    unsigned short* wel = weh + (size_t)NE * ND;
    unsigned short* wfh = wel + (size_t)NE * ND;
    unsigned short* wfl = wfh + (size_t)KF * ND;
    unsigned short* wend = wfl + (size_t)KF * ND;

    const size_t fixed = (size_t)((char*)wend - (char*)d_ws);
    int parts = 1;
    for (int p = 4; p >= 1; p >>= 1) {
        size_t need = fixed + ((p > 1) ? ((size_t)p * NM * NE * 4 + (size_t)p * NM * 8) : 0) + 256;
        if (ws_size >= need) { parts = p; break; }
    }
    float* pctx = (float*)wend;                          // parts x 16.8 MB (parts>1)
    float* Mpb  = pctx + ((parts > 1) ? (size_t)parts * NM * NE : 0);
    float* Lpb  = Mpb + (size_t)parts * NM;
    int*   flags = (int*)(Lpb + (size_t)parts * NM);

    k_detect<<<1, 256, 0, stream>>>(enc, mask, flags);
    k_split<<<(NB * NS * NE) / 2048, 256, 0, stream>>>(enc, flags, ehb, elb);
    k_split<<<(NM * ND) / 2048, 256, 0, stream>>>(dec, flags, dhb, dlb);
    k_split<<<(NE * ND) / 2048, 256, 0, stream>>>(Wenc, flags, weh, wel);
    k_twf<<<dim3(KF / 64, ND / 64), 256, 0, stream>>>(Wfin, flags, wfh, wfl);
    k_q_m<<<dim3(NM / 64, NE / 64), 256, 0, stream>>>(dhb, dlb, weh, wel, flags, qhb, qlb);
    k_attn<<<dim3(NT / 32, NB, parts), 256, 0, stream>>>(qhb, qlb, ehb, elb, mask, flags,
                                                         qhb, qlb, pctx, Mpb, Lpb);
    if (parts > 1)
        k_comb<<<NM / 8, 256, 0, stream>>>(pctx, Mpb, Lpb, parts, qhb, qlb);
    k_fin_m<<<dim3(NM / 64, ND / 64), 256, 0, stream>>>(qhb, qlb, dhb, dlb, wfh, wfl,
                                                        flags, d_out);
}

// Round 4
// 282.499 us; speedup vs baseline: 1.1345x; 1.1345x over previous
//
#include <hip/hip_runtime.h>
#include <math.h>
#include <stdint.h>

#define NB 16
#define NS 2048
#define NT 1024
#define NE 256
#define ND 256
#define NM (NB * NT)  // 16384
#define KF (NE + ND)  // 512

typedef short sh8 __attribute__((ext_vector_type(8)));
typedef float f4v __attribute__((ext_vector_type(4)));

// ---------------- dtype helpers ----------------
static __device__ __forceinline__ float bf2f(unsigned short u) {
    union { unsigned int i; float f; } v;
    v.i = ((unsigned int)u) << 16;
    return v.f;
}
static __device__ __forceinline__ unsigned short f2bf(float f) {
    union { unsigned int i; float f; } v;
    v.f = f;
    unsigned int x = v.i;
    x += 0x7FFFu + ((x >> 16) & 1u);  // round-to-nearest-even
    return (unsigned short)(x >> 16);
}
static __device__ __forceinline__ float4 load4(const void* p, int isbf, long idx) {
    if (isbf) {
        const unsigned short* h = (const unsigned short*)p + idx;
        ushort4 u = *(const ushort4*)h;
        return make_float4(bf2f(u.x), bf2f(u.y), bf2f(u.z), bf2f(u.w));
    }
    const float* f = (const float*)p + idx;
    return *(const float4*)f;
}
static __device__ __forceinline__ int mvalid(const void* m, int kind, int b, int s) {
    long idx = (long)b * NS + s;
    switch (kind) {
        case 0:  return ((const unsigned char*)m)[idx] != 0;
        case 1:  return ((const int*)m)[idx] != 0;
        case 2:  return ((const unsigned short*)m)[idx] != 0;
        default: return ((const unsigned int*)m)[idx] != 0;
    }
}

// ---------------- dtype detector ----------------
__global__ void k_detect(const void* __restrict__ enc_raw,
                         const void* __restrict__ mask_raw,
                         int* __restrict__ flags) {
    __shared__ int cnt;
    if (threadIdx.x == 0) cnt = 0;
    __syncthreads();
    const unsigned short* h = (const unsigned short*)enc_raw;
    int local = 0;
    for (int i = threadIdx.x; i < 4096; i += 256) {
        int ex = (h[i] >> 7) & 0xFF;
        if (ex >= 97 && ex <= 157) local++;
    }
    atomicAdd(&cnt, local);
    __syncthreads();
    if (threadIdx.x == 0) {
        int isbf = (cnt >= 3700) ? 1 : 0;
        const unsigned char* mb = (const unsigned char*)mask_raw;
        int kind;
        if (mb[1] == 0x3F)                       kind = 2;
        else if (mb[3] == 0x3F && mb[1] == 0)    kind = 3;
        else if (mb[1] == 1)                     kind = 0;
        else if (mb[4] == 1 || mb[8] == 1)       kind = 1;
        else                                     kind = (mb[NS] == 1) ? 0 : 1;
        flags[0] = isbf;
        flags[1] = kind;
    }
}

// ---------------- generic hi/lo bf16 split (8 elems / thread) ----------------
__global__ __launch_bounds__(256) void k_split(const void* __restrict__ src,
                                               const int* __restrict__ flags,
                                               unsigned short* __restrict__ hh,
                                               unsigned short* __restrict__ ll) {
    const int isbf = flags[0];
    const long i = ((long)blockIdx.x * 256 + threadIdx.x) * 8;
    if (isbf) {
        sh8 v = *(const sh8*)((const unsigned short*)src + i);
        *(sh8*)(hh + i) = v;   // ll never read in bf16 path
    } else {
        const float* f = (const float*)src + i;
        sh8 hv, lv;
#pragma unroll
        for (int j = 0; j < 8; ++j) {
            float x = f[j];
            unsigned short h = f2bf(x);
            hv[j] = (short)h;
            lv[j] = (short)f2bf(x - bf2f(h));
        }
        *(sh8*)(hh + i) = hv;
        *(sh8*)(ll + i) = lv;
    }
}

// ---------------- transpose + split W_fin: (512,256) -> [n][f] hi/lo ----------------
__global__ __launch_bounds__(256) void k_twf(const void* __restrict__ Wfin,
                                             const int* __restrict__ flags,
                                             unsigned short* __restrict__ wfh,
                                             unsigned short* __restrict__ wfl) {
    const int isbf = flags[0];
    __shared__ float T[64][68];
    const int f0 = blockIdx.x * 64, n0 = blockIdx.y * 64;
    const int tid = threadIdx.x;
#pragma unroll
    for (int i = 0; i < 4; ++i) {
        int idx = tid + i * 256;
        int r = idx >> 4, c4 = (idx & 15) << 2;
        float4 v = load4(Wfin, isbf, (long)(f0 + r) * ND + n0 + c4);
        T[r][c4] = v.x; T[r][c4 + 1] = v.y; T[r][c4 + 2] = v.z; T[r][c4 + 3] = v.w;
    }
    __syncthreads();
#pragma unroll
    for (int i = 0; i < 4; ++i) {
        int idx = tid + i * 256;
        int n = idx >> 4, f4 = (idx & 15) << 2;
        ushort4 hv, lv;
        float x;
        x = T[f4 + 0][n]; hv.x = f2bf(x); lv.x = f2bf(x - bf2f(hv.x));
        x = T[f4 + 1][n]; hv.y = f2bf(x); lv.y = f2bf(x - bf2f(hv.y));
        x = T[f4 + 2][n]; hv.z = f2bf(x); lv.z = f2bf(x - bf2f(hv.z));
        x = T[f4 + 3][n]; hv.w = f2bf(x); lv.w = f2bf(x - bf2f(hv.w));
        long base = (long)(n0 + n) * KF + f0 + f4;
        *(ushort4*)&wfh[base] = hv;
        *(ushort4*)&wfl[base] = lv;
    }
}

// ---------------- K1: qproj = dec @ Wenc^T via MFMA bf16x3 (LDS-staged B) --------
// Block 128m x 64n, 4 waves each 32m x 64n. B panel (64 n-rows x K=256, hi+lo)
// staged once in LDS; A fragments streamed from global (L2-resident).
__global__ __launch_bounds__(256) void k_q_m(const unsigned short* __restrict__ dh,
                                             const unsigned short* __restrict__ dl,
                                             const unsigned short* __restrict__ wh,
                                             const unsigned short* __restrict__ wl,
                                             const int* __restrict__ flags,
                                             unsigned short* __restrict__ qh,
                                             unsigned short* __restrict__ ql) {
    const int isbf = flags[0];
    const int tid = threadIdx.x;
    const int lane = tid & 63, wid = tid >> 6;
    const int lr = lane & 15, lg = lane >> 4;
    const long m0 = (long)blockIdx.x * 128 + wid * 32;
    const int  n0 = blockIdx.y * 64;
    __shared__ __align__(16) unsigned short Bh_s[64][264];
    __shared__ __align__(16) unsigned short Bl_s[64][264];
    // ---- stage B panel (once) ----
    {
        const int row = tid >> 2, seg = (tid & 3) * 64;
        const unsigned short* src = wh + (long)(n0 + row) * ND + seg;
#pragma unroll
        for (int c = 0; c < 8; ++c)
            *(sh8*)&Bh_s[row][seg + c * 8] = *(const sh8*)(src + c * 8);
        if (!isbf) {
            const unsigned short* src2 = wl + (long)(n0 + row) * ND + seg;
#pragma unroll
            for (int c = 0; c < 8; ++c)
                *(sh8*)&Bl_s[row][seg + c * 8] = *(const sh8*)(src2 + c * 8);
        }
    }
    __syncthreads();
    const unsigned short* Ah = dh + (m0 + lr) * ND + lg * 8;
    const unsigned short* Al = dl + (m0 + lr) * ND + lg * 8;
    f4v acc[2][4];
#pragma unroll
    for (int i = 0; i < 2; ++i)
#pragma unroll
        for (int j = 0; j < 4; ++j) acc[i][j] = (f4v){0.f, 0.f, 0.f, 0.f};
    if (isbf) {
#pragma unroll
        for (int k8 = 0; k8 < 8; ++k8) {
            const int ko = k8 * 32;
            sh8 a0 = *(const sh8*)(Ah + ko);
            sh8 a1 = *(const sh8*)(Ah + 16 * ND + ko);
#pragma unroll
            for (int ni = 0; ni < 4; ++ni) {
                sh8 b = *(const sh8*)&Bh_s[ni * 16 + lr][ko + lg * 8];
                acc[0][ni] = __builtin_amdgcn_mfma_f32_16x16x32_bf16(a0, b, acc[0][ni], 0, 0, 0);
                acc[1][ni] = __builtin_amdgcn_mfma_f32_16x16x32_bf16(a1, b, acc[1][ni], 0, 0, 0);
            }
        }
    } else {
#pragma unroll
        for (int k8 = 0; k8 < 8; ++k8) {
            const int ko = k8 * 32;
            sh8 a0 = *(const sh8*)(Ah + ko);
            sh8 a1 = *(const sh8*)(Ah + 16 * ND + ko);
            sh8 la0 = *(const sh8*)(Al + ko);
            sh8 la1 = *(const sh8*)(Al + 16 * ND + ko);
#pragma unroll
            for (int ni = 0; ni < 4; ++ni) {
                sh8 b  = *(const sh8*)&Bh_s[ni * 16 + lr][ko + lg * 8];
                sh8 lb = *(const sh8*)&Bl_s[ni * 16 + lr][ko + lg * 8];
                acc[0][ni] = __builtin_amdgcn_mfma_f32_16x16x32_bf16(a0, b, acc[0][ni], 0, 0, 0);
                acc[0][ni] = __builtin_amdgcn_mfma_f32_16x16x32_bf16(la0, b, acc[0][ni], 0, 0, 0);
                acc[0][ni] = __builtin_amdgcn_mfma_f32_16x16x32_bf16(a0, lb, acc[0][ni], 0, 0, 0);
                acc[1][ni] = __builtin_amdgcn_mfma_f32_16x16x32_bf16(a1, b, acc[1][ni], 0, 0, 0);
                acc[1][ni] = __builtin_amdgcn_mfma_f32_16x16x32_bf16(la1, b, acc[1][ni], 0, 0, 0);
                acc[1][ni] = __builtin_amdgcn_mfma_f32_16x16x32_bf16(a1, lb, acc[1][ni], 0, 0, 0);
            }
        }
    }
#pragma unroll
    for (int mi = 0; mi < 2; ++mi)
#pragma unroll
        for (int r = 0; r < 4; ++r) {
            long rowb = (m0 + mi * 16 + lg * 4 + r) * NE + n0 + lr;
#pragma unroll
            for (int ni = 0; ni < 4; ++ni) {
                float v = acc[mi][ni][r];
                unsigned short h = f2bf(v);
                qh[rowb + ni * 16] = h;
                ql[rowb + ni * 16] = f2bf(v - bf2f(h));
            }
        }
}

// ---------------- K2: MFMA flash attention (unchanged) ----------------
__global__ __launch_bounds__(256, 2) void k_attn(
    const unsigned short* qh, const unsigned short* ql,
    const unsigned short* __restrict__ eh, const unsigned short* __restrict__ el,
    const void* __restrict__ mask, const int* __restrict__ flags,
    unsigned short* ch, unsigned short* cl,
    float* __restrict__ pctx, float* __restrict__ Mp, float* __restrict__ Lp)
{
    const int isbf  = flags[0];
    const int mkind = flags[1];
    const int b  = blockIdx.y;
    const int t0 = blockIdx.x * 32;
    const int part = blockIdx.z, nparts = gridDim.z;
    const int tid  = threadIdx.x;
    const int lane = tid & 63;
    const int wid  = tid >> 6;
    const int th = wid & 1;
    const int sh = wid >> 1;
    const int lr = lane & 15;
    const int lg = lane >> 4;

    __shared__ __align__(16) unsigned short EHR[32][264];
    __shared__ __align__(16) unsigned short ELR[32][264];
    __shared__ __align__(16) unsigned short VT[2][256][40];
    __shared__ __align__(16) float PBs[32][36];
    __shared__ float hm[2][32];
    __shared__ float hs[2][32];
    __shared__ int s_len;

    if (tid == 0) s_len = 0;
    __syncthreads();
    {
        int c = 0;
#pragma unroll
        for (int j = 0; j < 8; ++j) c += mvalid(mask, mkind, b, tid * 8 + j);
        atomicAdd(&s_len, c);
    }
    __syncthreads();
    const int len  = s_len;
    const int s_lo = part * (NS / nparts);
    const int s_hi = min(s_lo + NS / nparts, len);
    const int ntiles = (s_hi > s_lo) ? ((s_hi - s_lo + 31) >> 5) : 0;
    const long mrow = (long)part * NM + (long)b * NT + t0;
    if (ntiles == 0) {
        if (nparts > 1 && tid < 32) { Mp[mrow + tid] = -INFINITY; Lp[mrow + tid] = 0.f; }
        return;
    }

    sh8 qhf[8], qlf[8];
    {
        const unsigned short* qp  = qh + ((long)b * NT + t0 + th * 16 + lr) * NE + lg * 8;
        const unsigned short* qp2 = ql + ((long)b * NT + t0 + th * 16 + lr) * NE + lg * 8;
#pragma unroll
        for (int k8 = 0; k8 < 8; ++k8) {
            qhf[k8] = *(const sh8*)(qp  + k8 * 32);
            qlf[k8] = *(const sh8*)(qp2 + k8 * 32);
        }
    }

    f4v O[8];
#pragma unroll
    for (int et = 0; et < 8; ++et) O[et] = (f4v){0.f, 0.f, 0.f, 0.f};
    float Mreg4[4], L4[4], MregP = -INFINITY;
#pragma unroll
    for (int r = 0; r < 4; ++r) { Mreg4[r] = -INFINITY; L4[r] = 0.f; }

    const int ss = tid >> 3;
    const int ee = (tid & 7) * 8;
    const int swzw = ((tid & 7) & 3) << 3;

    sh8 rh[4], rl[4];
    {
        const unsigned short* eg = eh + ((long)b * NS + s_lo + ss) * NE;
#pragma unroll
        for (int c = 0; c < 4; ++c) rh[c] = *(const sh8*)(eg + ee + c * 64);
        if (!isbf) {
            const unsigned short* eg2 = el + ((long)b * NS + s_lo + ss) * NE;
#pragma unroll
            for (int c = 0; c < 4; ++c) rl[c] = *(const sh8*)(eg2 + ee + c * 64);
        }
#pragma unroll
        for (int c = 0; c < 4; ++c) {
            const int e0 = ee + c * 64;
            *(sh8*)&EHR[ss][e0] = rh[c];
            if (!isbf) *(sh8*)&ELR[ss][e0] = rl[c];
            const int cs = ss ^ swzw;
#pragma unroll
            for (int j = 0; j < 8; ++j) VT[0][e0 + j][cs] = (unsigned short)rh[c][j];
        }
    }
    int cur = 0;

    for (int it = 0; it < ntiles; ++it) {
        const int s0 = s_lo + it * 32;
        __syncthreads();
        f4v cacc = (f4v){0.f, 0.f, 0.f, 0.f};
        {
            const unsigned short* ep = &EHR[sh * 16 + lr][lg * 8];
            const unsigned short* lp = &ELR[sh * 16 + lr][lg * 8];
            if (isbf) {
#pragma unroll
                for (int k8 = 0; k8 < 8; ++k8) {
                    sh8 ea = *(const sh8*)(ep + k8 * 32);
                    cacc = __builtin_amdgcn_mfma_f32_16x16x32_bf16(ea, qhf[k8], cacc, 0, 0, 0);
                    cacc = __builtin_amdgcn_mfma_f32_16x16x32_bf16(ea, qlf[k8], cacc, 0, 0, 0);
                }
            } else {
#pragma unroll
                for (int k8 = 0; k8 < 8; ++k8) {
                    sh8 ea = *(const sh8*)(ep + k8 * 32);
                    sh8 eb = *(const sh8*)(lp + k8 * 32);
                    cacc = __builtin_amdgcn_mfma_f32_16x16x32_bf16(ea, qhf[k8], cacc, 0, 0, 0);
                    cacc = __builtin_amdgcn_mfma_f32_16x16x32_bf16(ea, qlf[k8], cacc, 0, 0, 0);
                    cacc = __builtin_amdgcn_mfma_f32_16x16x32_bf16(eb, qhf[k8], cacc, 0, 0, 0);
                }
            }
        }
        float sc[4];
#pragma unroll
        for (int r = 0; r < 4; ++r) {
            int sl = sh * 16 + lg * 4 + r;
            sc[r] = (s0 + sl < len) ? cacc[r] : -INFINITY;
        }
        float m4 = fmaxf(fmaxf(sc[0], sc[1]), fmaxf(sc[2], sc[3]));
        m4 = fmaxf(m4, __shfl_xor(m4, 16));
        m4 = fmaxf(m4, __shfl_xor(m4, 32));
        float p[4], ps = 0.f;
#pragma unroll
        for (int r = 0; r < 4; ++r) {
            p[r] = (sc[r] == -INFINITY) ? 0.f : __expf(sc[r] - m4);
            ps += p[r];
        }
        ps += __shfl_xor(ps, 16);
        ps += __shfl_xor(ps, 32);
        if (lane < 16) { hm[sh][th * 16 + lane] = m4; hs[sh][th * 16 + lane] = ps; }
        *(float4*)&PBs[th * 16 + lr][sh * 16 + lg * 4] = make_float4(p[0], p[1], p[2], p[3]);
        __syncthreads();
        float f0, f1, al[4];
        {
            const int tP = th * 16 + lr;
            float h0 = hm[0][tP], h1 = hm[1][tP];
            float Mn = fmaxf(MregP, fmaxf(h0, h1));
            f0 = __expf(h0 - Mn);
            f1 = __expf(h1 - Mn);
            MregP = Mn;
        }
#pragma unroll
        for (int r = 0; r < 4; ++r) {
            const int t4 = th * 16 + lg * 4 + r;
            float g0 = hm[0][t4], g1 = hm[1][t4];
            float Mn = fmaxf(Mreg4[r], fmaxf(g0, g1));
            al[r] = __expf(Mreg4[r] - Mn);
            L4[r] = L4[r] * al[r] + hs[0][t4] * __expf(g0 - Mn) + hs[1][t4] * __expf(g1 - Mn);
            Mreg4[r] = Mn;
        }
        const int more = (it + 1 < ntiles);
        if (more) {
            const unsigned short* eg = eh + ((long)b * NS + s0 + 32 + ss) * NE;
#pragma unroll
            for (int c = 0; c < 4; ++c) rh[c] = *(const sh8*)(eg + ee + c * 64);
            if (!isbf) {
                const unsigned short* eg2 = el + ((long)b * NS + s0 + 32 + ss) * NE;
#pragma unroll
                for (int c = 0; c < 4; ++c) rl[c] = *(const sh8*)(eg2 + ee + c * 64);
            }
        }
        {
            const float fsc = (lg < 2) ? f0 : f1;
            f4v pA = *(const f4v*)&PBs[th * 16 + lr][lg * 8];
            f4v pB = *(const f4v*)&PBs[th * 16 + lr][lg * 8 + 4];
            sh8 pf;
#pragma unroll
            for (int j = 0; j < 4; ++j) {
                pf[j]     = (short)f2bf(pA[j] * fsc);
                pf[4 + j] = (short)f2bf(pB[j] * fsc);
            }
            f4v alv = (f4v){al[0], al[1], al[2], al[3]};
#pragma unroll
            for (int et = 0; et < 8; ++et) O[et] *= alv;
#pragma unroll
            for (int et = 0; et < 8; ++et) {
                const int row = sh * 128 + et * 16 + lr;
                sh8 vf = *(const sh8*)&VT[cur][row][(lg ^ ((row >> 3) & 3)) * 8];
                O[et] = __builtin_amdgcn_mfma_f32_16x16x32_bf16(pf, vf, O[et], 0, 0, 0);
            }
        }
        if (more) {
#pragma unroll
            for (int c = 0; c < 4; ++c) {
                const int e0 = ee + c * 64;
                *(sh8*)&EHR[ss][e0] = rh[c];
                if (!isbf) *(sh8*)&ELR[ss][e0] = rl[c];
                const int cs = ss ^ swzw;
#pragma unroll
                for (int j = 0; j < 8; ++j) VT[cur ^ 1][e0 + j][cs] = (unsigned short)rh[c][j];
            }
            cur ^= 1;
        }
    }
    if (nparts == 1) {
        f4v inv;
#pragma unroll
        for (int r = 0; r < 4; ++r) inv[r] = 1.0f / L4[r];
#pragma unroll
        for (int et = 0; et < 8; ++et) {
            f4v ov = O[et] * inv;
            long rbase = ((long)b * NT + t0 + th * 16 + lg * 4) * NE + sh * 128 + et * 16 + lr;
#pragma unroll
            for (int r = 0; r < 4; ++r) {
                float v = ov[r];
                unsigned short h = f2bf(v);
                ch[rbase + (long)r * NE] = h;
                cl[rbase + (long)r * NE] = f2bf(v - bf2f(h));
            }
        }
    } else {
        float* op = pctx + (long)part * NM * NE;
#pragma unroll
        for (int et = 0; et < 8; ++et) {
            long rbase = ((long)b * NT + t0 + th * 16 + lg * 4) * NE + sh * 128 + et * 16 + lr;
#pragma unroll
            for (int r = 0; r < 4; ++r)
                op[rbase + (long)r * NE] = O[et][r];
        }
        if (sh == 0 && lr == 0) {
#pragma unroll
            for (int r = 0; r < 4; ++r) {
                Mp[mrow + th * 16 + lg * 4 + r] = Mreg4[r];
                Lp[mrow + th * 16 + lg * 4 + r] = L4[r];
            }
        }
    }
}

// ---------------- combine split-s partials -> ctx bf16 hi/lo ----------------
__global__ __launch_bounds__(256) void k_comb(const float* __restrict__ pctx,
                                              const float* __restrict__ Mp,
                                              const float* __restrict__ Lp,
                                              int nparts,
                                              unsigned short* __restrict__ ch,
                                              unsigned short* __restrict__ cl) {
    const long m = (long)blockIdx.x * 8 + (threadIdx.x >> 5);
    const int  e0 = (threadIdx.x & 31) * 8;
    float Mv[4], Lv[4];
    float M = -INFINITY;
    for (int p = 0; p < nparts; ++p) {
        Mv[p] = Mp[(long)p * NM + m];
        Lv[p] = Lp[(long)p * NM + m];
        if (Lv[p] > 0.f) M = fmaxf(M, Mv[p]);
    }
    float L = 0.f, w[4];
    for (int p = 0; p < nparts; ++p) {
        w[p] = (Lv[p] > 0.f) ? __expf(Mv[p] - M) : 0.f;
        L += Lv[p] * w[p];
    }
    float o[8] = {};
    for (int p = 0; p < nparts; ++p) {
        if (w[p] > 0.f) {
            const float* src = pctx + (long)p * NM * NE + m * NE + e0;
            f4v a = *(const f4v*)src;
            f4v c = *(const f4v*)(src + 4);
#pragma unroll
            for (int j = 0; j < 4; ++j) { o[j] += a[j] * w[p]; o[4 + j] += c[j] * w[p]; }
        }
    }
    const float inv = 1.0f / L;
    unsigned short hv[8], lv[8];
#pragma unroll
    for (int j = 0; j < 8; ++j) {
        float v = o[j] * inv;
        unsigned short h = f2bf(v);
        hv[j] = h;
        lv[j] = f2bf(v - bf2f(h));
    }
    long base = m * NE + e0;
    *(ushort4*)&ch[base]     = *(ushort4*)&hv[0];
    *(ushort4*)&ch[base + 4] = *(ushort4*)&hv[4];
    *(ushort4*)&cl[base]     = *(ushort4*)&lv[0];
    *(ushort4*)&cl[base + 4] = *(ushort4*)&lv[4];
}

// ---------------- K3: out = tanh([ctx | dec] @ W_fin) via MFMA bf16x3 ------------
// Block 128m x 64n, 4 waves each 32m x 64n. B-hi panel (64 x 512) staged in LDS;
// B-lo (fp32 path) from global/L2; A fragments from global.
__global__ __launch_bounds__(256) void k_fin_m(const unsigned short* __restrict__ ch,
                                               const unsigned short* __restrict__ cl,
                                               const unsigned short* __restrict__ dh,
                                               const unsigned short* __restrict__ dl,
                                               const unsigned short* __restrict__ wh,
                                               const unsigned short* __restrict__ wl,
                                               const int* __restrict__ flags,
                                               void* __restrict__ out) {
    const int isbf = flags[0];
    const int tid = threadIdx.x;
    const int lane = tid & 63, wid = tid >> 6;
    const int lr = lane & 15, lg = lane >> 4;
    const long m0 = (long)blockIdx.x * 128 + wid * 32;
    const int  n0 = blockIdx.y * 64;
    __shared__ __align__(16) unsigned short Bh_s[64][520];
    // ---- stage B-hi panel (once): 64 rows x 512 ----
    {
        const int row = tid >> 2, seg = (tid & 3) * 128;
        const unsigned short* src = wh + (long)(n0 + row) * KF + seg;
#pragma unroll
        for (int c = 0; c < 16; ++c)
            *(sh8*)&Bh_s[row][seg + c * 8] = *(const sh8*)(src + c * 8);
    }
    __syncthreads();
    f4v acc[2][4];
#pragma unroll
    for (int i = 0; i < 2; ++i)
#pragma unroll
        for (int j = 0; j < 4; ++j) acc[i][j] = (f4v){0.f, 0.f, 0.f, 0.f};

#pragma unroll
    for (int k8 = 0; k8 < 16; ++k8) {
        const int ko = k8 * 32;
        // A fragments: ctx for k<256, dec for k>=256
        const unsigned short* Ahp = (k8 < 8) ? (ch + (m0 + lr) * NE + ko + lg * 8)
                                             : (dh + (m0 + lr) * ND + (ko - NE) + lg * 8);
        const unsigned short* Alp = (k8 < 8) ? (cl + (m0 + lr) * NE + ko + lg * 8)
                                             : (dl + (m0 + lr) * ND + (ko - NE) + lg * 8);
        const int astr = (k8 < 8) ? NE : ND;
        sh8 a0 = *(const sh8*)(Ahp);
        sh8 a1 = *(const sh8*)(Ahp + 16 * astr);
        if (isbf) {
#pragma unroll
            for (int ni = 0; ni < 4; ++ni) {
                sh8 b = *(const sh8*)&Bh_s[ni * 16 + lr][ko + lg * 8];
                acc[0][ni] = __builtin_amdgcn_mfma_f32_16x16x32_bf16(a0, b, acc[0][ni], 0, 0, 0);
                acc[1][ni] = __builtin_amdgcn_mfma_f32_16x16x32_bf16(a1, b, acc[1][ni], 0, 0, 0);
            }
        } else {
            sh8 la0 = *(const sh8*)(Alp);
            sh8 la1 = *(const sh8*)(Alp + 16 * astr);
            const unsigned short* Blp = wl + (long)(n0 + lr) * KF + ko + lg * 8;
#pragma unroll
            for (int ni = 0; ni < 4; ++ni) {
                sh8 b  = *(const sh8*)&Bh_s[ni * 16 + lr][ko + lg * 8];
                sh8 lb = *(const sh8*)(Blp + (long)ni * 16 * KF);
                acc[0][ni] = __builtin_amdgcn_mfma_f32_16x16x32_bf16(a0, b, acc[0][ni], 0, 0, 0);
                acc[0][ni] = __builtin_amdgcn_mfma_f32_16x16x32_bf16(la0, b, acc[0][ni], 0, 0, 0);
                acc[0][ni] = __builtin_amdgcn_mfma_f32_16x16x32_bf16(a0, lb, acc[0][ni], 0, 0, 0);
                acc[1][ni] = __builtin_amdgcn_mfma_f32_16x16x32_bf16(a1, b, acc[1][ni], 0, 0, 0);
                acc[1][ni] = __builtin_amdgcn_mfma_f32_16x16x32_bf16(la1, b, acc[1][ni], 0, 0, 0);
                acc[1][ni] = __builtin_amdgcn_mfma_f32_16x16x32_bf16(a1, lb, acc[1][ni], 0, 0, 0);
            }
        }
    }
    if (isbf) {
        unsigned short* o = (unsigned short*)out;
#pragma unroll
        for (int mi = 0; mi < 2; ++mi)
#pragma unroll
            for (int r = 0; r < 4; ++r) {
                long rowb = (m0 + mi * 16 + lg * 4 + r) * ND + n0 + lr;
#pragma unroll
                for (int ni = 0; ni < 4; ++ni)
                    o[rowb + ni * 16] = f2bf(tanhf(acc[mi][ni][r]));
            }
    } else {
        float* o = (float*)out;
#pragma unroll
        for (int mi = 0; mi < 2; ++mi)
#pragma unroll
            for (int r = 0; r < 4; ++r) {
                long rowb = (m0 + mi * 16 + lg * 4 + r) * ND + n0 + lr;
#pragma unroll
                for (int ni = 0; ni < 4; ++ni)
                    o[rowb + ni * 16] = tanhf(acc[mi][ni][r]);
            }
    }
}

extern "C" void kernel_launch(void* const* d_in, const int* in_sizes, int n_in,
                              void* d_out, int out_size, void* d_ws, size_t ws_size,
                              hipStream_t stream) {
    const void* enc  = d_in[0];  // (B,S,E)
    const void* dec  = d_in[1];  // (B,T,D)
    const void* mask = d_in[2];  // (B,S) bool
    const void* Wenc = d_in[3];  // (E,D)
    const void* Wfin = d_in[4];  // (E+D,D)

    unsigned short* ehb = (unsigned short*)d_ws;
    unsigned short* elb = ehb + (size_t)NB * NS * NE;
    unsigned short* qhb = elb + (size_t)NB * NS * NE;   // reused as ctx-hi after k_attn
    unsigned short* qlb = qhb + (size_t)NM * NE;        // reused as ctx-lo
    unsigned short* dhb = qlb + (size_t)NM * NE;
    unsigned short* dlb = dhb + (size_t)NM * ND;
    unsigned short* weh = dlb + (size_t)NM * ND;
    unsigned short* wel = weh + (size_t)NE * ND;
    unsigned short* wfh = wel + (size_t)NE * ND;
    unsigned short* wfl = wfh + (size_t)KF * ND;
    unsigned short* wend = wfl + (size_t)KF * ND;

    const size_t fixed = (size_t)((char*)wend - (char*)d_ws);
    int parts = 1;
    for (int p = 4; p >= 1; p >>= 1) {
        size_t need = fixed + ((p > 1) ? ((size_t)p * NM * NE * 4 + (size_t)p * NM * 8) : 0) + 256;
        if (ws_size >= need) { parts = p; break; }
    }
    float* pctx = (float*)wend;
    float* Mpb  = pctx + ((parts > 1) ? (size_t)parts * NM * NE : 0);
    float* Lpb  = Mpb + (size_t)parts * NM;
    int*   flags = (int*)(Lpb + (size_t)parts * NM);

    k_detect<<<1, 256, 0, stream>>>(enc, mask, flags);
    k_split<<<(NB * NS * NE) / 2048, 256, 0, stream>>>(enc, flags, ehb, elb);
    k_split<<<(NM * ND) / 2048, 256, 0, stream>>>(dec, flags, dhb, dlb);
    k_split<<<(NE * ND) / 2048, 256, 0, stream>>>(Wenc, flags, weh, wel);
    k_twf<<<dim3(KF / 64, ND / 64), 256, 0, stream>>>(Wfin, flags, wfh, wfl);
    k_q_m<<<dim3(NM / 128, NE / 64), 256, 0, stream>>>(dhb, dlb, weh, wel, flags, qhb, qlb);
    k_attn<<<dim3(NT / 32, NB, parts), 256, 0, stream>>>(qhb, qlb, ehb, elb, mask, flags,
                                                         qhb, qlb, pctx, Mpb, Lpb);
    if (parts > 1)
        k_comb<<<NM / 8, 256, 0, stream>>>(pctx, Mpb, Lpb, parts, qhb, qlb);
    k_fin_m<<<dim3(NM / 128, ND / 64), 256, 0, stream>>>(qhb, qlb, dhb, dlb, wfh, wfl,
                                                         flags, d_out);
}

// Round 5
// 266.729 us; speedup vs baseline: 1.2016x; 1.0591x over previous
//
#include <hip/hip_runtime.h>
#include <math.h>
#include <stdint.h>

#define NB 16
#define NS 2048
#define NT 1024
#define NE 256
#define ND 256
#define NM (NB * NT)  // 16384
#define KF (NE + ND)  // 512

typedef short sh8 __attribute__((ext_vector_type(8)));
typedef float f4v __attribute__((ext_vector_type(4)));

// ---------------- dtype helpers ----------------
static __device__ __forceinline__ float bf2f(unsigned short u) {
    union { unsigned int i; float f; } v;
    v.i = ((unsigned int)u) << 16;
    return v.f;
}
static __device__ __forceinline__ unsigned short f2bf(float f) {
    union { unsigned int i; float f; } v;
    v.f = f;
    unsigned int x = v.i;
    x += 0x7FFFu + ((x >> 16) & 1u);  // round-to-nearest-even
    return (unsigned short)(x >> 16);
}
static __device__ __forceinline__ float4 load4(const void* p, int isbf, long idx) {
    if (isbf) {
        const unsigned short* h = (const unsigned short*)p + idx;
        ushort4 u = *(const ushort4*)h;
        return make_float4(bf2f(u.x), bf2f(u.y), bf2f(u.z), bf2f(u.w));
    }
    const float* f = (const float*)p + idx;
    return *(const float4*)f;
}
static __device__ __forceinline__ int mvalid(const void* m, int kind, int b, int s) {
    long idx = (long)b * NS + s;
    switch (kind) {
        case 0:  return ((const unsigned char*)m)[idx] != 0;
        case 1:  return ((const int*)m)[idx] != 0;
        case 2:  return ((const unsigned short*)m)[idx] != 0;
        default: return ((const unsigned int*)m)[idx] != 0;
    }
}

// ---------------- dtype detector ----------------
__global__ void k_detect(const void* __restrict__ enc_raw,
                         const void* __restrict__ mask_raw,
                         int* __restrict__ flags) {
    __shared__ int cnt;
    if (threadIdx.x == 0) cnt = 0;
    __syncthreads();
    const unsigned short* h = (const unsigned short*)enc_raw;
    int local = 0;
    for (int i = threadIdx.x; i < 4096; i += 256) {
        int ex = (h[i] >> 7) & 0xFF;
        if (ex >= 97 && ex <= 157) local++;
    }
    atomicAdd(&cnt, local);
    __syncthreads();
    if (threadIdx.x == 0) {
        int isbf = (cnt >= 3700) ? 1 : 0;
        const unsigned char* mb = (const unsigned char*)mask_raw;
        int kind;
        if (mb[1] == 0x3F)                       kind = 2;
        else if (mb[3] == 0x3F && mb[1] == 0)    kind = 3;
        else if (mb[1] == 1)                     kind = 0;
        else if (mb[4] == 1 || mb[8] == 1)       kind = 1;
        else                                     kind = (mb[NS] == 1) ? 0 : 1;
        flags[0] = isbf;
        flags[1] = kind;
    }
}

// ---------------- generic hi/lo bf16 split (8 elems / thread) ----------------
__global__ __launch_bounds__(256) void k_split(const void* __restrict__ src,
                                               const int* __restrict__ flags,
                                               unsigned short* __restrict__ hh,
                                               unsigned short* __restrict__ ll) {
    const int isbf = flags[0];
    const long i = ((long)blockIdx.x * 256 + threadIdx.x) * 8;
    if (isbf) {
        sh8 v = *(const sh8*)((const unsigned short*)src + i);
        *(sh8*)(hh + i) = v;   // ll never read in bf16 path
    } else {
        const float* f = (const float*)src + i;
        sh8 hv, lv;
#pragma unroll
        for (int j = 0; j < 8; ++j) {
            float x = f[j];
            unsigned short h = f2bf(x);
            hv[j] = (short)h;
            lv[j] = (short)f2bf(x - bf2f(h));
        }
        *(sh8*)(hh + i) = hv;
        *(sh8*)(ll + i) = lv;
    }
}

// ---------------- transpose + split W_fin: (512,256) -> [n][f] hi/lo ----------------
__global__ __launch_bounds__(256) void k_twf(const void* __restrict__ Wfin,
                                             const int* __restrict__ flags,
                                             unsigned short* __restrict__ wfh,
                                             unsigned short* __restrict__ wfl) {
    const int isbf = flags[0];
    __shared__ float T[64][68];
    const int f0 = blockIdx.x * 64, n0 = blockIdx.y * 64;
    const int tid = threadIdx.x;
#pragma unroll
    for (int i = 0; i < 4; ++i) {
        int idx = tid + i * 256;
        int r = idx >> 4, c4 = (idx & 15) << 2;
        float4 v = load4(Wfin, isbf, (long)(f0 + r) * ND + n0 + c4);
        T[r][c4] = v.x; T[r][c4 + 1] = v.y; T[r][c4 + 2] = v.z; T[r][c4 + 3] = v.w;
    }
    __syncthreads();
#pragma unroll
    for (int i = 0; i < 4; ++i) {
        int idx = tid + i * 256;
        int n = idx >> 4, f4 = (idx & 15) << 2;
        ushort4 hv, lv;
        float x;
        x = T[f4 + 0][n]; hv.x = f2bf(x); lv.x = f2bf(x - bf2f(hv.x));
        x = T[f4 + 1][n]; hv.y = f2bf(x); lv.y = f2bf(x - bf2f(hv.y));
        x = T[f4 + 2][n]; hv.z = f2bf(x); lv.z = f2bf(x - bf2f(hv.z));
        x = T[f4 + 3][n]; hv.w = f2bf(x); lv.w = f2bf(x - bf2f(hv.w));
        long base = (long)(n0 + n) * KF + f0 + f4;
        *(ushort4*)&wfh[base] = hv;
        *(ushort4*)&wfl[base] = lv;
    }
}

// ---------------- K1: qproj = dec @ Wenc^T via MFMA bf16x3 (LDS-staged B) --------
// 1D grid 512; decode groups the 4 n-panels of one m-panel onto the SAME XCD
// (bid&7 fixes m%8) so A re-reads hit that XCD's L2.
__global__ __launch_bounds__(256) void k_q_m(const unsigned short* __restrict__ dh,
                                             const unsigned short* __restrict__ dl,
                                             const unsigned short* __restrict__ wh,
                                             const unsigned short* __restrict__ wl,
                                             const int* __restrict__ flags,
                                             unsigned short* __restrict__ qh,
                                             unsigned short* __restrict__ ql) {
    const int isbf = flags[0];
    const int tid = threadIdx.x;
    const int lane = tid & 63, wid = tid >> 6;
    const int lr = lane & 15, lg = lane >> 4;
    const int bid = blockIdx.x;
    const int mblk = (bid & 7) + (((bid >> 3) >> 2) << 3);  // 0..127
    const int nblk = (bid >> 3) & 3;                        // 0..3
    const long m0 = (long)mblk * 128 + wid * 32;
    const int  n0 = nblk * 64;
    __shared__ __align__(16) unsigned short Bh_s[64][264];
    __shared__ __align__(16) unsigned short Bl_s[64][264];
    // ---- stage B panel (once) ----
    {
        const int row = tid >> 2, seg = (tid & 3) * 64;
        const unsigned short* src = wh + (long)(n0 + row) * ND + seg;
#pragma unroll
        for (int c = 0; c < 8; ++c)
            *(sh8*)&Bh_s[row][seg + c * 8] = *(const sh8*)(src + c * 8);
        if (!isbf) {
            const unsigned short* src2 = wl + (long)(n0 + row) * ND + seg;
#pragma unroll
            for (int c = 0; c < 8; ++c)
                *(sh8*)&Bl_s[row][seg + c * 8] = *(const sh8*)(src2 + c * 8);
        }
    }
    __syncthreads();
    const unsigned short* Ah = dh + (m0 + lr) * ND + lg * 8;
    const unsigned short* Al = dl + (m0 + lr) * ND + lg * 8;
    f4v acc[2][4];
#pragma unroll
    for (int i = 0; i < 2; ++i)
#pragma unroll
        for (int j = 0; j < 4; ++j) acc[i][j] = (f4v){0.f, 0.f, 0.f, 0.f};
    if (isbf) {
#pragma unroll
        for (int k8 = 0; k8 < 8; ++k8) {
            const int ko = k8 * 32;
            sh8 a0 = *(const sh8*)(Ah + ko);
            sh8 a1 = *(const sh8*)(Ah + 16 * ND + ko);
#pragma unroll
            for (int ni = 0; ni < 4; ++ni) {
                sh8 b = *(const sh8*)&Bh_s[ni * 16 + lr][ko + lg * 8];
                acc[0][ni] = __builtin_amdgcn_mfma_f32_16x16x32_bf16(a0, b, acc[0][ni], 0, 0, 0);
                acc[1][ni] = __builtin_amdgcn_mfma_f32_16x16x32_bf16(a1, b, acc[1][ni], 0, 0, 0);
            }
        }
    } else {
#pragma unroll
        for (int k8 = 0; k8 < 8; ++k8) {
            const int ko = k8 * 32;
            sh8 a0 = *(const sh8*)(Ah + ko);
            sh8 a1 = *(const sh8*)(Ah + 16 * ND + ko);
            sh8 la0 = *(const sh8*)(Al + ko);
            sh8 la1 = *(const sh8*)(Al + 16 * ND + ko);
#pragma unroll
            for (int ni = 0; ni < 4; ++ni) {
                sh8 b  = *(const sh8*)&Bh_s[ni * 16 + lr][ko + lg * 8];
                sh8 lb = *(const sh8*)&Bl_s[ni * 16 + lr][ko + lg * 8];
                acc[0][ni] = __builtin_amdgcn_mfma_f32_16x16x32_bf16(a0, b, acc[0][ni], 0, 0, 0);
                acc[0][ni] = __builtin_amdgcn_mfma_f32_16x16x32_bf16(la0, b, acc[0][ni], 0, 0, 0);
                acc[0][ni] = __builtin_amdgcn_mfma_f32_16x16x32_bf16(a0, lb, acc[0][ni], 0, 0, 0);
                acc[1][ni] = __builtin_amdgcn_mfma_f32_16x16x32_bf16(a1, b, acc[1][ni], 0, 0, 0);
                acc[1][ni] = __builtin_amdgcn_mfma_f32_16x16x32_bf16(la1, b, acc[1][ni], 0, 0, 0);
                acc[1][ni] = __builtin_amdgcn_mfma_f32_16x16x32_bf16(a1, lb, acc[1][ni], 0, 0, 0);
            }
        }
    }
#pragma unroll
    for (int mi = 0; mi < 2; ++mi)
#pragma unroll
        for (int r = 0; r < 4; ++r) {
            long rowb = (m0 + mi * 16 + lg * 4 + r) * NE + n0 + lr;
#pragma unroll
            for (int ni = 0; ni < 4; ++ni) {
                float v = acc[mi][ni][r];
                unsigned short h = f2bf(v);
                qh[rowb + ni * 16] = h;
                ql[rowb + ni * 16] = f2bf(v - bf2f(h));
            }
        }
}

// ---------------- K2: MFMA flash attention ----------------
// VT built by conflict-free LDS transpose (EHR column reads -> b128 writes),
// single-buffered. Scores use 3 independent accumulator chains (ILP).
__global__ __launch_bounds__(256, 2) void k_attn(
    const unsigned short* qh, const unsigned short* ql,
    const unsigned short* __restrict__ eh, const unsigned short* __restrict__ el,
    const void* __restrict__ mask, const int* __restrict__ flags,
    unsigned short* ch, unsigned short* cl,
    float* __restrict__ pctx, float* __restrict__ Mp, float* __restrict__ Lp)
{
    const int isbf  = flags[0];
    const int mkind = flags[1];
    const int b  = blockIdx.y;
    const int t0 = blockIdx.x * 32;
    const int part = blockIdx.z, nparts = gridDim.z;
    const int tid  = threadIdx.x;
    const int lane = tid & 63;
    const int wid  = tid >> 6;
    const int th = wid & 1;
    const int sh = wid >> 1;
    const int lr = lane & 15;
    const int lg = lane >> 4;

    __shared__ __align__(16) unsigned short EHR[32][264];
    __shared__ __align__(16) unsigned short ELR[32][264];
    __shared__ __align__(16) unsigned short VT[256][40];
    __shared__ __align__(16) float PBs[32][36];
    __shared__ float hm[2][32];
    __shared__ float hs[2][32];
    __shared__ int s_len;

    if (tid == 0) s_len = 0;
    __syncthreads();
    {
        int c = 0;
#pragma unroll
        for (int j = 0; j < 8; ++j) c += mvalid(mask, mkind, b, tid * 8 + j);
        atomicAdd(&s_len, c);
    }
    __syncthreads();
    const int len  = s_len;
    const int s_lo = part * (NS / nparts);
    const int s_hi = min(s_lo + NS / nparts, len);
    const int ntiles = (s_hi > s_lo) ? ((s_hi - s_lo + 31) >> 5) : 0;
    const long mrow = (long)part * NM + (long)b * NT + t0;
    if (ntiles == 0) {
        if (nparts > 1 && tid < 32) { Mp[mrow + tid] = -INFINITY; Lp[mrow + tid] = 0.f; }
        return;
    }

    sh8 qhf[8], qlf[8];
    {
        const unsigned short* qp  = qh + ((long)b * NT + t0 + th * 16 + lr) * NE + lg * 8;
        const unsigned short* qp2 = ql + ((long)b * NT + t0 + th * 16 + lr) * NE + lg * 8;
#pragma unroll
        for (int k8 = 0; k8 < 8; ++k8) {
            qhf[k8] = *(const sh8*)(qp  + k8 * 32);
            qlf[k8] = *(const sh8*)(qp2 + k8 * 32);
        }
    }

    f4v O[8];
#pragma unroll
    for (int et = 0; et < 8; ++et) O[et] = (f4v){0.f, 0.f, 0.f, 0.f};
    float Mreg4[4], L4[4], MregP = -INFINITY;
#pragma unroll
    for (int r = 0; r < 4; ++r) { Mreg4[r] = -INFINITY; L4[r] = 0.f; }

    const int ss = tid >> 3;
    const int ee = (tid & 7) * 8;

    sh8 rh[4], rl[4];
    // prologue: stage tile 0 (row-major only; VT built in-loop)
    {
        const unsigned short* eg = eh + ((long)b * NS + s_lo + ss) * NE;
#pragma unroll
        for (int c = 0; c < 4; ++c) rh[c] = *(const sh8*)(eg + ee + c * 64);
        if (!isbf) {
            const unsigned short* eg2 = el + ((long)b * NS + s_lo + ss) * NE;
#pragma unroll
            for (int c = 0; c < 4; ++c) rl[c] = *(const sh8*)(eg2 + ee + c * 64);
        }
#pragma unroll
        for (int c = 0; c < 4; ++c) {
            const int e0 = ee + c * 64;
            *(sh8*)&EHR[ss][e0] = rh[c];
            if (!isbf) *(sh8*)&ELR[ss][e0] = rl[c];
        }
    }

    for (int it = 0; it < ntiles; ++it) {
        const int s0 = s_lo + it * 32;
        __syncthreads();   // B2: stage(it) visible
        // ---- scores: 3 independent accumulator chains ----
        f4v cacc;
        {
            const unsigned short* ep = &EHR[sh * 16 + lr][lg * 8];
            const unsigned short* lp = &ELR[sh * 16 + lr][lg * 8];
            f4v c0 = (f4v){0.f, 0.f, 0.f, 0.f};
            f4v c1 = (f4v){0.f, 0.f, 0.f, 0.f};
            f4v c2 = (f4v){0.f, 0.f, 0.f, 0.f};
            if (isbf) {
#pragma unroll
                for (int k8 = 0; k8 < 8; ++k8) {
                    sh8 ea = *(const sh8*)(ep + k8 * 32);
                    c0 = __builtin_amdgcn_mfma_f32_16x16x32_bf16(ea, qhf[k8], c0, 0, 0, 0);
                    c1 = __builtin_amdgcn_mfma_f32_16x16x32_bf16(ea, qlf[k8], c1, 0, 0, 0);
                }
            } else {
#pragma unroll
                for (int k8 = 0; k8 < 8; ++k8) {
                    sh8 ea = *(const sh8*)(ep + k8 * 32);
                    sh8 eb = *(const sh8*)(lp + k8 * 32);
                    c0 = __builtin_amdgcn_mfma_f32_16x16x32_bf16(ea, qhf[k8], c0, 0, 0, 0);
                    c1 = __builtin_amdgcn_mfma_f32_16x16x32_bf16(ea, qlf[k8], c1, 0, 0, 0);
                    c2 = __builtin_amdgcn_mfma_f32_16x16x32_bf16(eb, qhf[k8], c2, 0, 0, 0);
                }
            }
            cacc = c0 + c1 + c2;
        }
        // ---- conflict-free transpose EHR -> VT (thread owns e-column tid) ----
        {
            unsigned short col[32];
#pragma unroll
            for (int s = 0; s < 32; ++s) col[s] = EHR[s][tid];
#pragma unroll
            for (int c = 0; c < 4; ++c)
                *(sh8*)&VT[tid][c * 8] = *(const sh8*)&col[c * 8];
        }
        // ---- per-half softmax publish ----
        float sc[4];
#pragma unroll
        for (int r = 0; r < 4; ++r) {
            int sl = sh * 16 + lg * 4 + r;
            sc[r] = (s0 + sl < len) ? cacc[r] : -INFINITY;
        }
        float m4 = fmaxf(fmaxf(sc[0], sc[1]), fmaxf(sc[2], sc[3]));
        m4 = fmaxf(m4, __shfl_xor(m4, 16));
        m4 = fmaxf(m4, __shfl_xor(m4, 32));
        float p[4], ps = 0.f;
#pragma unroll
        for (int r = 0; r < 4; ++r) {
            p[r] = (sc[r] == -INFINITY) ? 0.f : __expf(sc[r] - m4);
            ps += p[r];
        }
        ps += __shfl_xor(ps, 16);
        ps += __shfl_xor(ps, 32);
        if (lane < 16) { hm[sh][th * 16 + lane] = m4; hs[sh][th * 16 + lane] = ps; }
        *(float4*)&PBs[th * 16 + lr][sh * 16 + lg * 4] = make_float4(p[0], p[1], p[2], p[3]);
        // ---- issue next-tile global loads (hidden under barrier + PV) ----
        const int more = (it + 1 < ntiles);
        if (more) {
            const unsigned short* eg = eh + ((long)b * NS + s0 + 32 + ss) * NE;
#pragma unroll
            for (int c = 0; c < 4; ++c) rh[c] = *(const sh8*)(eg + ee + c * 64);
            if (!isbf) {
                const unsigned short* eg2 = el + ((long)b * NS + s0 + 32 + ss) * NE;
#pragma unroll
                for (int c = 0; c < 4; ++c) rl[c] = *(const sh8*)(eg2 + ee + c * 64);
            }
        }
        __syncthreads();   // B5: publish + VT visible (all EHR/ELR reads done)
        // ---- register (M,L) update ----
        float f0, f1, al[4];
        {
            const int tP = th * 16 + lr;
            float h0 = hm[0][tP], h1 = hm[1][tP];
            float Mn = fmaxf(MregP, fmaxf(h0, h1));
            f0 = __expf(h0 - Mn);
            f1 = __expf(h1 - Mn);
            MregP = Mn;
        }
#pragma unroll
        for (int r = 0; r < 4; ++r) {
            const int t4 = th * 16 + lg * 4 + r;
            float g0 = hm[0][t4], g1 = hm[1][t4];
            float Mn = fmaxf(Mreg4[r], fmaxf(g0, g1));
            al[r] = __expf(Mreg4[r] - Mn);
            L4[r] = L4[r] * al[r] + hs[0][t4] * __expf(g0 - Mn) + hs[1][t4] * __expf(g1 - Mn);
            Mreg4[r] = Mn;
        }
        // ---- PV ----
        {
            const float fsc = (lg < 2) ? f0 : f1;
            f4v pA = *(const f4v*)&PBs[th * 16 + lr][lg * 8];
            f4v pB = *(const f4v*)&PBs[th * 16 + lr][lg * 8 + 4];
            sh8 pf;
#pragma unroll
            for (int j = 0; j < 4; ++j) {
                pf[j]     = (short)f2bf(pA[j] * fsc);
                pf[4 + j] = (short)f2bf(pB[j] * fsc);
            }
            f4v alv = (f4v){al[0], al[1], al[2], al[3]};
#pragma unroll
            for (int et = 0; et < 8; ++et) O[et] *= alv;
#pragma unroll
            for (int et = 0; et < 8; ++et) {
                sh8 vf = *(const sh8*)&VT[sh * 128 + et * 16 + lr][lg * 8];
                O[et] = __builtin_amdgcn_mfma_f32_16x16x32_bf16(pf, vf, O[et], 0, 0, 0);
            }
        }
        // ---- write staged regs -> EHR/ELR (next tile) ----
        if (more) {
#pragma unroll
            for (int c = 0; c < 4; ++c) {
                const int e0 = ee + c * 64;
                *(sh8*)&EHR[ss][e0] = rh[c];
                if (!isbf) *(sh8*)&ELR[ss][e0] = rl[c];
            }
        }
    }
    // ---- epilogue ----
    if (nparts == 1) {
        f4v inv;
#pragma unroll
        for (int r = 0; r < 4; ++r) inv[r] = 1.0f / L4[r];
#pragma unroll
        for (int et = 0; et < 8; ++et) {
            f4v ov = O[et] * inv;
            long rbase = ((long)b * NT + t0 + th * 16 + lg * 4) * NE + sh * 128 + et * 16 + lr;
#pragma unroll
            for (int r = 0; r < 4; ++r) {
                float v = ov[r];
                unsigned short h = f2bf(v);
                ch[rbase + (long)r * NE] = h;
                cl[rbase + (long)r * NE] = f2bf(v - bf2f(h));
            }
        }
    } else {
        float* op = pctx + (long)part * NM * NE;
#pragma unroll
        for (int et = 0; et < 8; ++et) {
            long rbase = ((long)b * NT + t0 + th * 16 + lg * 4) * NE + sh * 128 + et * 16 + lr;
#pragma unroll
            for (int r = 0; r < 4; ++r)
                op[rbase + (long)r * NE] = O[et][r];
        }
        if (sh == 0 && lr == 0) {
#pragma unroll
            for (int r = 0; r < 4; ++r) {
                Mp[mrow + th * 16 + lg * 4 + r] = Mreg4[r];
                Lp[mrow + th * 16 + lg * 4 + r] = L4[r];
            }
        }
    }
}

// ---------------- combine split-s partials -> ctx bf16 hi/lo ----------------
__global__ __launch_bounds__(256) void k_comb(const float* __restrict__ pctx,
                                              const float* __restrict__ Mp,
                                              const float* __restrict__ Lp,
                                              int nparts,
                                              unsigned short* __restrict__ ch,
                                              unsigned short* __restrict__ cl) {
    const long m = (long)blockIdx.x * 8 + (threadIdx.x >> 5);
    const int  e0 = (threadIdx.x & 31) * 8;
    float Mv[4], Lv[4];
    float M = -INFINITY;
    for (int p = 0; p < nparts; ++p) {
        Mv[p] = Mp[(long)p * NM + m];
        Lv[p] = Lp[(long)p * NM + m];
        if (Lv[p] > 0.f) M = fmaxf(M, Mv[p]);
    }
    float L = 0.f, w[4];
    for (int p = 0; p < nparts; ++p) {
        w[p] = (Lv[p] > 0.f) ? __expf(Mv[p] - M) : 0.f;
        L += Lv[p] * w[p];
    }
    float o[8] = {};
    for (int p = 0; p < nparts; ++p) {
        if (w[p] > 0.f) {
            const float* src = pctx + (long)p * NM * NE + m * NE + e0;
            f4v a = *(const f4v*)src;
            f4v c = *(const f4v*)(src + 4);
#pragma unroll
            for (int j = 0; j < 4; ++j) { o[j] += a[j] * w[p]; o[4 + j] += c[j] * w[p]; }
        }
    }
    const float inv = 1.0f / L;
    unsigned short hv[8], lv[8];
#pragma unroll
    for (int j = 0; j < 8; ++j) {
        float v = o[j] * inv;
        unsigned short h = f2bf(v);
        hv[j] = h;
        lv[j] = f2bf(v - bf2f(h));
    }
    long base = m * NE + e0;
    *(ushort4*)&ch[base]     = *(ushort4*)&hv[0];
    *(ushort4*)&ch[base + 4] = *(ushort4*)&hv[4];
    *(ushort4*)&cl[base]     = *(ushort4*)&lv[0];
    *(ushort4*)&cl[base + 4] = *(ushort4*)&lv[4];
}

// ---------------- K3: out = tanh([ctx | dec] @ W_fin) via MFMA bf16x3 ------------
// 1D grid 512, XCD-grouped decode. Two k-phases; per phase the B panel
// (hi AND lo) is staged in LDS -> no per-wave global B re-reads.
__global__ __launch_bounds__(256) void k_fin_m(const unsigned short* __restrict__ ch,
                                               const unsigned short* __restrict__ cl,
                                               const unsigned short* __restrict__ dh,
                                               const unsigned short* __restrict__ dl,
                                               const unsigned short* __restrict__ wh,
                                               const unsigned short* __restrict__ wl,
                                               const int* __restrict__ flags,
                                               void* __restrict__ out) {
    const int isbf = flags[0];
    const int tid = threadIdx.x;
    const int lane = tid & 63, wid = tid >> 6;
    const int lr = lane & 15, lg = lane >> 4;
    const int bid = blockIdx.x;
    const int mblk = (bid & 7) + (((bid >> 3) >> 2) << 3);
    const int nblk = (bid >> 3) & 3;
    const long m0 = (long)mblk * 128 + wid * 32;
    const int  n0 = nblk * 64;
    __shared__ __align__(16) unsigned short Bh_s[64][264];
    __shared__ __align__(16) unsigned short Bl_s[64][264];
    const int row = tid >> 2, seg = (tid & 3) * 64;
    f4v acc[2][4];
#pragma unroll
    for (int i = 0; i < 2; ++i)
#pragma unroll
        for (int j = 0; j < 4; ++j) acc[i][j] = (f4v){0.f, 0.f, 0.f, 0.f};

#pragma unroll
    for (int ph = 0; ph < 2; ++ph) {
        if (ph) __syncthreads();  // prev-phase LDS reads complete before overwrite
        {
            const unsigned short* src = wh + (long)(n0 + row) * KF + ph * 256 + seg;
#pragma unroll
            for (int c = 0; c < 8; ++c)
                *(sh8*)&Bh_s[row][seg + c * 8] = *(const sh8*)(src + c * 8);
            if (!isbf) {
                const unsigned short* src2 = wl + (long)(n0 + row) * KF + ph * 256 + seg;
#pragma unroll
                for (int c = 0; c < 8; ++c)
                    *(sh8*)&Bl_s[row][seg + c * 8] = *(const sh8*)(src2 + c * 8);
            }
        }
        __syncthreads();
        const unsigned short* Ah = (ph == 0 ? ch : dh) + (m0 + lr) * 256 + lg * 8;
        const unsigned short* Al = (ph == 0 ? cl : dl) + (m0 + lr) * 256 + lg * 8;
        if (isbf) {
            // bf16 inputs: hi-only operands (phase 0 ctx-lo ignored, matches r4 semantics)
#pragma unroll
            for (int k8 = 0; k8 < 8; ++k8) {
                const int ko = k8 * 32;
                sh8 a0 = *(const sh8*)(Ah + ko);
                sh8 a1 = *(const sh8*)(Ah + 16 * 256 + ko);
#pragma unroll
                for (int ni = 0; ni < 4; ++ni) {
                    sh8 b = *(const sh8*)&Bh_s[ni * 16 + lr][ko + lg * 8];
                    acc[0][ni] = __builtin_amdgcn_mfma_f32_16x16x32_bf16(a0, b, acc[0][ni], 0, 0, 0);
                    acc[1][ni] = __builtin_amdgcn_mfma_f32_16x16x32_bf16(a1, b, acc[1][ni], 0, 0, 0);
                }
            }
        } else {
#pragma unroll
            for (int k8 = 0; k8 < 8; ++k8) {
                const int ko = k8 * 32;
                sh8 a0 = *(const sh8*)(Ah + ko);
                sh8 a1 = *(const sh8*)(Ah + 16 * 256 + ko);
                sh8 la0 = *(const sh8*)(Al + ko);
                sh8 la1 = *(const sh8*)(Al + 16 * 256 + ko);
#pragma unroll
                for (int ni = 0; ni < 4; ++ni) {
                    sh8 b  = *(const sh8*)&Bh_s[ni * 16 + lr][ko + lg * 8];
                    sh8 lb = *(const sh8*)&Bl_s[ni * 16 + lr][ko + lg * 8];
                    acc[0][ni] = __builtin_amdgcn_mfma_f32_16x16x32_bf16(a0, b, acc[0][ni], 0, 0, 0);
                    acc[0][ni] = __builtin_amdgcn_mfma_f32_16x16x32_bf16(la0, b, acc[0][ni], 0, 0, 0);
                    acc[0][ni] = __builtin_amdgcn_mfma_f32_16x16x32_bf16(a0, lb, acc[0][ni], 0, 0, 0);
                    acc[1][ni] = __builtin_amdgcn_mfma_f32_16x16x32_bf16(a1, b, acc[1][ni], 0, 0, 0);
                    acc[1][ni] = __builtin_amdgcn_mfma_f32_16x16x32_bf16(la1, b, acc[1][ni], 0, 0, 0);
                    acc[1][ni] = __builtin_amdgcn_mfma_f32_16x16x32_bf16(a1, lb, acc[1][ni], 0, 0, 0);
                }
            }
        }
    }
    if (isbf) {
        unsigned short* o = (unsigned short*)out;
#pragma unroll
        for (int mi = 0; mi < 2; ++mi)
#pragma unroll
            for (int r = 0; r < 4; ++r) {
                long rowb = (m0 + mi * 16 + lg * 4 + r) * ND + n0 + lr;
#pragma unroll
                for (int ni = 0; ni < 4; ++ni)
                    o[rowb + ni * 16] = f2bf(tanhf(acc[mi][ni][r]));
            }
    } else {
        float* o = (float*)out;
#pragma unroll
        for (int mi = 0; mi < 2; ++mi)
#pragma unroll
            for (int r = 0; r < 4; ++r) {
                long rowb = (m0 + mi * 16 + lg * 4 + r) * ND + n0 + lr;
#pragma unroll
                for (int ni = 0; ni < 4; ++ni)
                    o[rowb + ni * 16] = tanhf(acc[mi][ni][r]);
            }
    }
}

extern "C" void kernel_launch(void* const* d_in, const int* in_sizes, int n_in,
                              void* d_out, int out_size, void* d_ws, size_t ws_size,
                              hipStream_t stream) {
    const void* enc  = d_in[0];  // (B,S,E)
    const void* dec  = d_in[1];  // (B,T,D)
    const void* mask = d_in[2];  // (B,S) bool
    const void* Wenc = d_in[3];  // (E,D)
    const void* Wfin = d_in[4];  // (E+D,D)

    unsigned short* ehb = (unsigned short*)d_ws;
    unsigned short* elb = ehb + (size_t)NB * NS * NE;
    unsigned short* qhb = elb + (size_t)NB * NS * NE;   // reused as ctx-hi after k_attn
    unsigned short* qlb = qhb + (size_t)NM * NE;        // reused as ctx-lo
    unsigned short* dhb = qlb + (size_t)NM * NE;
    unsigned short* dlb = dhb + (size_t)NM * ND;
    unsigned short* weh = dlb + (size_t)NM * ND;
    unsigned short* wel = weh + (size_t)NE * ND;
    unsigned short* wfh = wel + (size_t)NE * ND;
    unsigned short* wfl = wfh + (size_t)KF * ND;
    unsigned short* wend = wfl + (size_t)KF * ND;

    const size_t fixed = (size_t)((char*)wend - (char*)d_ws);
    int parts = 1;
    for (int p = 4; p >= 1; p >>= 1) {
        size_t need = fixed + ((p > 1) ? ((size_t)p * NM * NE * 4 + (size_t)p * NM * 8) : 0) + 256;
        if (ws_size >= need) { parts = p; break; }
    }
    float* pctx = (float*)wend;
    float* Mpb  = pctx + ((parts > 1) ? (size_t)parts * NM * NE : 0);
    float* Lpb  = Mpb + (size_t)parts * NM;
    int*   flags = (int*)(Lpb + (size_t)parts * NM);

    k_detect<<<1, 256, 0, stream>>>(enc, mask, flags);
    k_split<<<(NB * NS * NE) / 2048, 256, 0, stream>>>(enc, flags, ehb, elb);
    k_split<<<(NM * ND) / 2048, 256, 0, stream>>>(dec, flags, dhb, dlb);
    k_split<<<(NE * ND) / 2048, 256, 0, stream>>>(Wenc, flags, weh, wel);
    k_twf<<<dim3(KF / 64, ND / 64), 256, 0, stream>>>(Wfin, flags, wfh, wfl);
    k_q_m<<<512, 256, 0, stream>>>(dhb, dlb, weh, wel, flags, qhb, qlb);
    k_attn<<<dim3(NT / 32, NB, parts), 256, 0, stream>>>(qhb, qlb, ehb, elb, mask, flags,
                                                         qhb, qlb, pctx, Mpb, Lpb);
    if (parts > 1)
        k_comb<<<NM / 8, 256, 0, stream>>>(pctx, Mpb, Lpb, parts, qhb, qlb);
    k_fin_m<<<512, 256, 0, stream>>>(qhb, qlb, dhb, dlb, wfh, wfl, flags, d_out);
}